// Round 8
// baseline (610.145 us; speedup 1.0000x reference)
//
#include <hip/hip_runtime.h>
#include <hip/hip_bf16.h>

// ---------------------------------------------------------------------------
// PointPillars encoder.
// R8: conv occupancy fix. R7 convs were latency-bound (MfmaUtil 26%, VALUBusy
//     12%, occupancy 20%: grid 512 = exactly 2 blocks/CU, ~1.6 waves/SIMD).
//     TY 16->8 (conv1a/1b) and 8->4 (conv2a/2b): 1024 blocks = 4 blocks/CU,
//     smaller LDS (23/13.8 KB), MT=2/1 -> lower VGPR -> 4 waves/SIMD.
// Convs remain MFMA bf16 hi/lo split (3 terms), fp32 accum.
// ---------------------------------------------------------------------------

#define NXG 256
#define NYG 256

typedef unsigned short u16;
typedef unsigned int u32;
typedef __attribute__((ext_vector_type(8))) short sx8;   // 8 bf16 (4 VGPR)
typedef __attribute__((ext_vector_type(4))) float fx4;   // 4 f32
typedef __attribute__((ext_vector_type(4))) u32 ux4;     // 16B

// round-to-nearest-even fp32 -> bf16 bits
__device__ __forceinline__ u16 f2bf(float x) {
    u32 u = __float_as_uint(x);
    return (u16)((u + 0x7fffu + ((u >> 16) & 1u)) >> 16);
}

// ---- weight repack + split: OIHW fp32 -> [t][co][ci] bf16 hi/lo ----------
__global__ __launch_bounds__(256) void repack_wb(const float* __restrict__ src,
                                                 u16* __restrict__ dh,
                                                 u16* __restrict__ dl,
                                                 int Cin, int Cout) {
    int i = blockIdx.x * 256 + threadIdx.x;
    int total = Cout * Cin * 9;
    if (i >= total) return;
    int co = i / (Cin * 9);
    int r  = i - co * (Cin * 9);
    int ci = r / 9;
    int t  = r - ci * 9;          // t = ky*3+kx
    float w = src[i];
    u16 h = f2bf(w);
    float hf = __uint_as_float((u32)h << 16);
    u16 l = f2bf(w - hf);
    size_t di = ((size_t)t * Cout + co) * Cin + ci;
    dh[di] = h;
    dl[di] = l;
}

__global__ void h2zero_k(const float* __restrict__ t1, const float* __restrict__ w2,
                         const float* __restrict__ s2, const float* __restrict__ t2,
                         float* __restrict__ h2z) {
    int co = threadIdx.x;  // 64 threads
    float acc = 0.f;
    for (int j = 0; j < 32; j++) {
        float h1 = fmaxf(t1[j], 0.f);
        acc += h1 * w2[j * 64 + co];
    }
    h2z[co] = fmaxf(acc * s2[co] + t2[co], 0.f);
}

// ---- point stage ----------------------------------------------------------

__global__ __launch_bounds__(256) void count_pts(const float4* __restrict__ pts, int n,
                                                 int* __restrict__ cnt,
                                                 int* __restrict__ cellof) {
    int i = blockIdx.x * 256 + threadIdx.x;
    if (i >= n) return;
    float4 p = pts[i];
    int cell = -1;
    if (p.x >= -51.2f && p.x < 51.2f && p.y >= -51.2f && p.y < 51.2f) {
        // IEEE division to match reference floor((x - X_MIN)/X_RES) exactly.
        float qx = (p.x + 51.2f) / 0.4f;
        float qy = (p.y + 51.2f) / 0.4f;
        int xi = (int)floorf(qx); xi = xi < 0 ? 0 : (xi > 255 ? 255 : xi);
        int yi = (int)floorf(qy); yi = yi < 0 ? 0 : (yi > 255 ? 255 : yi);
        cell = yi * NXG + xi;
        atomicAdd(&cnt[cell], 1);
    }
    cellof[i] = cell;
}

__global__ __launch_bounds__(256) void scan1(const int* __restrict__ cnt,
                                             int* __restrict__ scnt,
                                             int* __restrict__ bsum,
                                             int* __restrict__ cur) {
    __shared__ int sm[256];
    int b = blockIdx.x, t = threadIdx.x;
    int v = cnt[b * 256 + t];
    sm[t] = v;
    __syncthreads();
    for (int off = 1; off < 256; off <<= 1) {
        int x = (t >= off) ? sm[t - off] : 0;
        __syncthreads();
        sm[t] += x;
        __syncthreads();
    }
    scnt[b * 256 + t] = sm[t] - v;       // exclusive
    if (t == 255) bsum[b] = sm[t];
    cur[b * 256 + t] = 0;
}

__global__ __launch_bounds__(256) void scan2(const int* __restrict__ bsum,
                                             int* __restrict__ boff,
                                             int* __restrict__ dT) {
    __shared__ int sm[256];
    int t = threadIdx.x;
    int v = bsum[t];
    sm[t] = v;
    __syncthreads();
    for (int off = 1; off < 256; off <<= 1) {
        int x = (t >= off) ? sm[t - off] : 0;
        __syncthreads();
        sm[t] += x;
        __syncthreads();
    }
    boff[t] = sm[t] - v;                 // exclusive
    if (t == 255) dT[0] = sm[t];
}

__global__ __launch_bounds__(256) void place_pts(const float4* __restrict__ pts, int n,
                                                 const int* __restrict__ cellof,
                                                 const int* __restrict__ scnt,
                                                 const int* __restrict__ boff,
                                                 int* __restrict__ cur,
                                                 float* __restrict__ fcomp) {
    int i = blockIdx.x * 256 + threadIdx.x;
    if (i >= n) return;
    int cell = cellof[i];
    if (cell < 0) return;
    int slot = atomicAdd(&cur[cell], 1);
    if (slot >= 32) return;  // P(cell>32 pts) ~ 1e-30 at lambda~2.6
    int pos = boff[cell >> 8] + scnt[cell] + slot;
    float4 p = pts[i];
    int xi = cell & 255, yi = cell >> 8;
    float cx = (float)xi * 0.4f + -51.0f;
    float cy = (float)yi * 0.4f + -51.0f;
    float4* d = (float4*)(fcomp + (size_t)pos * 8);
    d[0] = make_float4(p.x, p.y, p.z, p.w);
    d[1] = make_float4(p.x - cx, p.y - cy, p.z, 0.f);
}

__global__ __launch_bounds__(256) void mlp_pts(
    const float* __restrict__ fcomp, const int* __restrict__ dT,
    const float* __restrict__ w1, const float* __restrict__ s1, const float* __restrict__ t1,
    const float* __restrict__ w2, const float* __restrict__ s2, const float* __restrict__ t2,
    float* __restrict__ hcomp) {
    int i = blockIdx.x * 256 + threadIdx.x;
    if (i >= dT[0]) return;
    const float4* f = (const float4*)(fcomp + (size_t)i * 8);
    float4 a = f[0], b = f[1];
    float h1[32];
#pragma unroll
    for (int k = 0; k < 32; k++) {
        float v = a.x * w1[0 * 32 + k] + a.y * w1[1 * 32 + k] + a.z * w1[2 * 32 + k]
                + a.w * w1[3 * 32 + k] + b.x * w1[4 * 32 + k] + b.y * w1[5 * 32 + k]
                + b.z * w1[6 * 32 + k];
        h1[k] = fmaxf(v * s1[k] + t1[k], 0.f);
    }
    float acc[64];
#pragma unroll
    for (int c = 0; c < 64; c++) acc[c] = 0.f;
#pragma unroll
    for (int k = 0; k < 32; k++) {
        float hk = h1[k];
#pragma unroll
        for (int c4 = 0; c4 < 16; c4++) {
            float4 wv = *(const float4*)&w2[k * 64 + c4 * 4];
            acc[c4 * 4 + 0] += hk * wv.x;
            acc[c4 * 4 + 1] += hk * wv.y;
            acc[c4 * 4 + 2] += hk * wv.z;
            acc[c4 * 4 + 3] += hk * wv.w;
        }
    }
    float* o = hcomp + (size_t)i * 64;
#pragma unroll
    for (int c4 = 0; c4 < 16; c4++) {
        float4 ov;
        ov.x = fmaxf(acc[c4 * 4 + 0] * s2[c4 * 4 + 0] + t2[c4 * 4 + 0], 0.f);
        ov.y = fmaxf(acc[c4 * 4 + 1] * s2[c4 * 4 + 1] + t2[c4 * 4 + 1], 0.f);
        ov.z = fmaxf(acc[c4 * 4 + 2] * s2[c4 * 4 + 2] + t2[c4 * 4 + 2], 0.f);
        ov.w = fmaxf(acc[c4 * 4 + 3] * s2[c4 * 4 + 3] + t2[c4 * 4 + 3], 0.f);
        *(float4*)&o[c4 * 4] = ov;
    }
}

// Wave per cell; writes bf16 hi/lo planes feeding conv1a.
__global__ __launch_bounds__(256) void cell_reduce(
    const int* __restrict__ cnt, const int* __restrict__ scnt,
    const int* __restrict__ boff, const float* __restrict__ hcomp,
    const float* __restrict__ h2z, u16* __restrict__ deschi, u16* __restrict__ desclo) {
    int cell = blockIdx.x * 4 + (threadIdx.x >> 6);
    int co = threadIdx.x & 63;
    int c = cnt[cell];
    int start = boff[cell >> 8] + scnt[cell];
    int cc = c < 32 ? c : 32;
    float m = (c > 0 && c < 32) ? h2z[co] : 0.f;
    const float* hp = hcomp + (size_t)start * 64 + co;
    for (int s = 0; s < cc; s++) m = fmaxf(m, hp[(size_t)s * 64]);
    u16 h = f2bf(m);
    float hf = __uint_as_float((u32)h << 16);
    u16 l = f2bf(m - hf);
    deschi[(size_t)cell * 64 + co] = h;
    desclo[(size_t)cell * 64 + co] = l;
}

// ---- MFMA conv ------------------------------------------------------------
// Implicit GEMM: D[pix][co] = sum_{t,ci} A[pix+shift(t)][ci] * W[t][co][ci].
// Block: 256 thr / 4 waves; pixel tile 16 x TY; co tile 64 (blockIdx.z).
// Wave: MT=TY/4 m-tiles (one 16-pixel y-row each) x 4 n-tiles (16 co each).
// A hi/lo staged in LDS per 32-ci chunk (halo 18 x (TY+2)); B hi/lo read
// from global (shared across waves -> L1). 3 MFMA per tile pair.
// Fragment maps (16x16x32 bf16): A row=lane&15, k=(lane>>4)*8+j;
// B col=lane&15, k=(lane>>4)*8+j; D col=lane&15, row=(lane>>4)*4+reg [m89].
template <int CIN, int COUT, int TY, bool WF32>
__global__ __launch_bounds__(256, 4) void conv3x3_mfma(
    const u16* __restrict__ inh, const u16* __restrict__ inl,
    const u16* __restrict__ wh, const u16* __restrict__ wl,
    const float* __restrict__ bs, const float* __restrict__ bt,
    u16* __restrict__ outh, u16* __restrict__ outl, float* __restrict__ outf) {
    constexpr int MT = (TY + 3) / 4;      // m-tiles per wave (TY=4 -> 1 row/wave)
    constexpr int HP = (TY + 2) * 18;     // halo pixels
    __shared__ u16 Ah[HP * 32];
    __shared__ u16 Al[HP * 32];

    const int tid = threadIdx.x;
    const int lane = tid & 63, wid = tid >> 6;
    const int bx = blockIdx.x, by = blockIdx.y;
    const int cob = blockIdx.z * 64;

    fx4 acc[MT][4];
#pragma unroll
    for (int mt = 0; mt < MT; mt++)
#pragma unroll
        for (int nt = 0; nt < 4; nt++) acc[mt][nt] = (fx4){0.f, 0.f, 0.f, 0.f};

    const int ax = lane & 15, akg = (lane >> 4) * 8;

#pragma unroll 1
    for (int cc = 0; cc < CIN / 32; ++cc) {
        if (cc) __syncthreads();
        // stage halo tile (hi+lo), 16B chunks; LDS writes are linear per wave
        for (int i = tid; i < HP * 4; i += 256) {
            int p = i >> 2, c = i & 3;
            int ty = p / 18, tx = p - ty * 18;
            int gy = by * TY + ty - 1, gx = bx * 16 + tx - 1;
            ux4 vh = (ux4){0u, 0u, 0u, 0u}, vl = vh;
            if (gy >= 0 && gy < NYG && gx >= 0 && gx < NXG) {
                size_t gi = ((size_t)(gy * NXG + gx)) * CIN + cc * 32 + c * 8;
                vh = *(const ux4*)&inh[gi];
                vl = *(const ux4*)&inl[gi];
            }
            *(ux4*)&Ah[p * 32 + c * 8] = vh;
            *(ux4*)&Al[p * 32 + c * 8] = vl;
        }
        __syncthreads();

#pragma unroll
        for (int t = 0; t < 9; ++t) {
            const int ky = t / 3, kx = t - (t / 3) * 3;
            // B frags from global (L1-hot: shared by all waves on the CU)
            const u16* wbh = wh + ((size_t)(t * COUT + cob)) * CIN + cc * 32;
            const u16* wbl = wl + ((size_t)(t * COUT + cob)) * CIN + cc * 32;
            sx8 bh[4], bl[4];
#pragma unroll
            for (int nt = 0; nt < 4; nt++) {
                size_t off = (size_t)(nt * 16 + ax) * CIN + akg;
                bh[nt] = *(const sx8*)&wbh[off];
                bl[nt] = *(const sx8*)&wbl[off];
            }
            // A frags from LDS
            sx8 ah[MT], al[MT];
#pragma unroll
            for (int mt = 0; mt < MT; mt++) {
                int prow = (wid * MT + mt + ky) * 18 + kx;
                int aoff = (prow + ax) * 32 + akg;
                ah[mt] = *(const sx8*)&Ah[aoff];
                al[mt] = *(const sx8*)&Al[aoff];
            }
#pragma unroll
            for (int mt = 0; mt < MT; mt++)
#pragma unroll
                for (int nt = 0; nt < 4; nt++) {
                    acc[mt][nt] = __builtin_amdgcn_mfma_f32_16x16x32_bf16(
                        al[mt], bh[nt], acc[mt][nt], 0, 0, 0);
                    acc[mt][nt] = __builtin_amdgcn_mfma_f32_16x16x32_bf16(
                        ah[mt], bl[nt], acc[mt][nt], 0, 0, 0);
                    acc[mt][nt] = __builtin_amdgcn_mfma_f32_16x16x32_bf16(
                        ah[mt], bh[nt], acc[mt][nt], 0, 0, 0);
                }
        }
    }

    // epilogue: D col(lane&15)=co-offset, row((lane>>4)*4+r)=x
    const int ex = (lane >> 4) * 4, eco = lane & 15;
#pragma unroll
    for (int mt = 0; mt < MT; mt++) {
        int y = by * TY + wid * MT + mt;
#pragma unroll
        for (int nt = 0; nt < 4; nt++) {
            int co = cob + nt * 16 + eco;
            float s = bs[co], b = bt[co];
#pragma unroll
            for (int r = 0; r < 4; r++) {
                int x = bx * 16 + ex + r;
                float v = fmaxf(acc[mt][nt][r] * s + b, 0.f);
                size_t pix = (size_t)y * NXG + x;
                if (WF32) {
                    outf[pix * COUT + co] = v;
                } else {
                    u16 h = f2bf(v);
                    float hf = __uint_as_float((u32)h << 16);
                    u16 l = f2bf(v - hf);
                    outh[pix * COUT + co] = h;
                    outl[pix * COUT + co] = l;
                }
            }
        }
    }
}

// fp32 NHWC [65536][64] -> NCHW [64][65536]
__global__ __launch_bounds__(256) void nhwc_to_nchw(const float* __restrict__ in,
                                                    float* __restrict__ out) {
    __shared__ float tl[64][65];
    int bp = blockIdx.x * 64;
    int t = threadIdx.x;
    int p = t >> 2, q = t & 3;
#pragma unroll
    for (int j = 0; j < 4; j++) {
        float4 v = *(const float4*)&in[(size_t)(bp + p) * 64 + q * 16 + j * 4];
        tl[p][q * 16 + j * 4 + 0] = v.x;
        tl[p][q * 16 + j * 4 + 1] = v.y;
        tl[p][q * 16 + j * 4 + 2] = v.z;
        tl[p][q * 16 + j * 4 + 3] = v.w;
    }
    __syncthreads();
    int co = t >> 2;
#pragma unroll
    for (int j = 0; j < 4; j++) {
        int pp = q * 16 + j * 4;
        float4 v = make_float4(tl[pp][co], tl[pp + 1][co], tl[pp + 2][co], tl[pp + 3][co]);
        *(float4*)&out[(size_t)co * 65536 + bp + pp] = v;
    }
}

extern "C" void kernel_launch(void* const* d_in, const int* in_sizes, int n_in,
                              void* d_out, int out_size, void* d_ws, size_t ws_size,
                              hipStream_t stream) {
    const float* points = (const float*)d_in[0];
    const float* w1 = (const float*)d_in[1];
    const float* s1 = (const float*)d_in[2];
    const float* t1 = (const float*)d_in[3];
    const float* w2 = (const float*)d_in[4];
    const float* s2 = (const float*)d_in[5];
    const float* t2 = (const float*)d_in[6];
    const float* cw1a = (const float*)d_in[7];
    const float* cs1a = (const float*)d_in[8];
    const float* ct1a = (const float*)d_in[9];
    const float* cw1b = (const float*)d_in[10];
    const float* cs1b = (const float*)d_in[11];
    const float* ct1b = (const float*)d_in[12];
    const float* cw2a = (const float*)d_in[13];
    const float* cs2a = (const float*)d_in[14];
    const float* ct2a = (const float*)d_in[15];
    const float* cw2b = (const float*)d_in[16];
    const float* cs2b = (const float*)d_in[17];
    const float* ct2b = (const float*)d_in[18];
    int n = in_sizes[0] / 4;

    // Workspace (max 91.2 MB; 98 MB proven OK in R2):
    //  <2M   small: cnt/scnt/cur/boff/dT/h2z/cellof/bsum
    //  2M    bf16 weights (1.27 MB)
    //  4M    fcomp 6.4M [dead after mlp_pts]
    //  12M   deschi 8M | 20M desclo 8M [dead after conv1a]
    //  40M   hcomp 51.2M [dead after cell_reduce]
    //  40M   X1h 16M | 56M X1l 16M (conv1a out) [alias hcomp; dead after conv1b]
    //  4M    X2h 16M | 20M X2l 16M (conv1b out) [alias fcomp+desc; dead after conv2a]
    //  72M   X3h 8M  | 80M X3l 8M  (conv2a out) [dead after conv2b]
    //  40M   X4 16M fp32 NHWC (conv2b out) [alias X1]
    char* ws = (char*)d_ws;
    int*   cnt    = (int*)(ws + 0);
    int*   scnt   = (int*)(ws + 262144);
    int*   cur    = (int*)(ws + 524288);
    int*   boff   = (int*)(ws + 786432);
    int*   dT     = (int*)(ws + 790528);
    float* h2z    = (float*)(ws + 794624);
    int*   cellof = (int*)(ws + (1ull << 20));
    int*   bsum   = (int*)(ws + (1ull << 20) + 819200);
    size_t W0 = 2ull << 20;
    u16* w1ah = (u16*)(ws + W0 + 0);
    u16* w1al = (u16*)(ws + W0 + 147456);
    u16* w1bh = (u16*)(ws + W0 + 294912);
    u16* w1bl = (u16*)(ws + W0 + 589824);
    u16* w2ah = (u16*)(ws + W0 + 884736);
    u16* w2al = (u16*)(ws + W0 + 1032192);
    u16* w2bh = (u16*)(ws + W0 + 1179648);
    u16* w2bl = (u16*)(ws + W0 + 1253376);
    float* fcomp  = (float*)(ws + (4ull << 20));
    u16*   deschi = (u16*)(ws + (12ull << 20));
    u16*   desclo = (u16*)(ws + (20ull << 20));
    float* hcomp  = (float*)(ws + (40ull << 20));
    u16*   X1h    = (u16*)(ws + (40ull << 20));
    u16*   X1l    = (u16*)(ws + (56ull << 20));
    u16*   X2h    = (u16*)(ws + (4ull << 20));
    u16*   X2l    = (u16*)(ws + (20ull << 20));
    u16*   X3h    = (u16*)(ws + (72ull << 20));
    u16*   X3l    = (u16*)(ws + (80ull << 20));
    float* X4     = (float*)(ws + (40ull << 20));

    hipMemsetAsync(cnt, 0, 262144, stream);

    repack_wb<<<(128 * 64 * 9 + 255) / 256, 256, 0, stream>>>(cw1a, w1ah, w1al, 64, 128);
    repack_wb<<<(128 * 128 * 9 + 255) / 256, 256, 0, stream>>>(cw1b, w1bh, w1bl, 128, 128);
    repack_wb<<<(64 * 128 * 9 + 255) / 256, 256, 0, stream>>>(cw2a, w2ah, w2al, 128, 64);
    repack_wb<<<(64 * 64 * 9 + 255) / 256, 256, 0, stream>>>(cw2b, w2bh, w2bl, 64, 64);
    h2zero_k<<<1, 64, 0, stream>>>(t1, w2, s2, t2, h2z);

    count_pts<<<(n + 255) / 256, 256, 0, stream>>>((const float4*)points, n, cnt, cellof);
    scan1<<<256, 256, 0, stream>>>(cnt, scnt, bsum, cur);
    scan2<<<1, 256, 0, stream>>>(bsum, boff, dT);
    place_pts<<<(n + 255) / 256, 256, 0, stream>>>((const float4*)points, n, cellof,
                                                   scnt, boff, cur, fcomp);
    mlp_pts<<<(n + 255) / 256, 256, 0, stream>>>(fcomp, dT, w1, s1, t1, w2, s2, t2, hcomp);
    cell_reduce<<<65536 / 4, 256, 0, stream>>>(cnt, scnt, boff, hcomp, h2z, deschi, desclo);

    conv3x3_mfma<64, 128, 8, false><<<dim3(16, 32, 2), 256, 0, stream>>>(
        deschi, desclo, w1ah, w1al, cs1a, ct1a, X1h, X1l, nullptr);
    conv3x3_mfma<128, 128, 8, false><<<dim3(16, 32, 2), 256, 0, stream>>>(
        X1h, X1l, w1bh, w1bl, cs1b, ct1b, X2h, X2l, nullptr);
    conv3x3_mfma<128, 64, 4, false><<<dim3(16, 64, 1), 256, 0, stream>>>(
        X2h, X2l, w2ah, w2al, cs2a, ct2a, X3h, X3l, nullptr);
    conv3x3_mfma<64, 64, 4, true><<<dim3(16, 64, 1), 256, 0, stream>>>(
        X3h, X3l, w2bh, w2bl, cs2b, ct2b, nullptr, nullptr, X4);
    nhwc_to_nchw<<<1024, 256, 0, stream>>>(X4, (float*)d_out);
}

// Round 10
// 300.116 us; speedup vs baseline: 2.0330x; 2.0330x over previous
//
#include <hip/hip_runtime.h>
#include <hip/hip_bf16.h>

// ---------------------------------------------------------------------------
// PointPillars encoder.
// R9/R10: conv rewrite. R7/R8 were L1-BW-bound on per-wave-redundant weight
//     fragments (util 26%/16% matched 128/256KB-per-CU-tap arithmetic).
//     Now: weights bf16 (no lo plane; quant err ~0.002/layer), activations
//     split hi/lo EXACTLY, fused as one k=32 MFMA: A_ext=[Ah|Al], W_ext=[W|W]
//     (k-groups 2,3 re-read same LDS bytes). B staged in LDS once per
//     block/chunk (18KB, 9 taps). XOR-swizzled A and B LDS layouts.
// Activations layout: [pix][ci-chunk of 16][hi 32B | lo 32B].
// ---------------------------------------------------------------------------

#define NXG 256
#define NYG 256

typedef unsigned short u16;
typedef unsigned int u32;
typedef __attribute__((ext_vector_type(8))) short sx8;   // 8 bf16 (4 VGPR)
typedef __attribute__((ext_vector_type(4))) float fx4;   // 4 f32
typedef __attribute__((ext_vector_type(4))) u32 ux4;     // 16B

__device__ __forceinline__ u16 f2bf(float x) {           // RNE fp32->bf16
    u32 u = __float_as_uint(x);
    return (u16)((u + 0x7fffu + ((u >> 16) & 1u)) >> 16);
}

// OIHW fp32 -> [ci-chunk][tap][co][16ci] bf16
__global__ __launch_bounds__(256) void repack_wv2(const float* __restrict__ src,
                                                  u16* __restrict__ dst,
                                                  int Cin, int Cout) {
    int i = blockIdx.x * 256 + threadIdx.x;
    int total = Cout * Cin * 9;
    if (i >= total) return;
    int co = i / (Cin * 9);
    int rr = i - co * (Cin * 9);
    int ci = rr / 9;
    int t  = rr - ci * 9;
    dst[(((size_t)(ci >> 4) * 9 + t) * Cout + co) * 16 + (ci & 15)] = f2bf(src[i]);
}

__global__ void h2zero_k(const float* __restrict__ t1, const float* __restrict__ w2,
                         const float* __restrict__ s2, const float* __restrict__ t2,
                         float* __restrict__ h2z) {
    int co = threadIdx.x;  // 64 threads
    float acc = 0.f;
    for (int j = 0; j < 32; j++) {
        float h1 = fmaxf(t1[j], 0.f);
        acc += h1 * w2[j * 64 + co];
    }
    h2z[co] = fmaxf(acc * s2[co] + t2[co], 0.f);
}

// ---- point stage (unchanged from R6) --------------------------------------

__global__ __launch_bounds__(256) void count_pts(const float4* __restrict__ pts, int n,
                                                 int* __restrict__ cnt,
                                                 int* __restrict__ cellof) {
    int i = blockIdx.x * 256 + threadIdx.x;
    if (i >= n) return;
    float4 p = pts[i];
    int cell = -1;
    if (p.x >= -51.2f && p.x < 51.2f && p.y >= -51.2f && p.y < 51.2f) {
        float qx = (p.x + 51.2f) / 0.4f;   // IEEE div matches reference floor
        float qy = (p.y + 51.2f) / 0.4f;
        int xi = (int)floorf(qx); xi = xi < 0 ? 0 : (xi > 255 ? 255 : xi);
        int yi = (int)floorf(qy); yi = yi < 0 ? 0 : (yi > 255 ? 255 : yi);
        cell = yi * NXG + xi;
        atomicAdd(&cnt[cell], 1);
    }
    cellof[i] = cell;
}

__global__ __launch_bounds__(256) void scan1(const int* __restrict__ cnt,
                                             int* __restrict__ scnt,
                                             int* __restrict__ bsum,
                                             int* __restrict__ cur) {
    __shared__ int sm[256];
    int b = blockIdx.x, t = threadIdx.x;
    int v = cnt[b * 256 + t];
    sm[t] = v;
    __syncthreads();
    for (int off = 1; off < 256; off <<= 1) {
        int x = (t >= off) ? sm[t - off] : 0;
        __syncthreads();
        sm[t] += x;
        __syncthreads();
    }
    scnt[b * 256 + t] = sm[t] - v;
    if (t == 255) bsum[b] = sm[t];
    cur[b * 256 + t] = 0;
}

__global__ __launch_bounds__(256) void scan2(const int* __restrict__ bsum,
                                             int* __restrict__ boff,
                                             int* __restrict__ dT) {
    __shared__ int sm[256];
    int t = threadIdx.x;
    int v = bsum[t];
    sm[t] = v;
    __syncthreads();
    for (int off = 1; off < 256; off <<= 1) {
        int x = (t >= off) ? sm[t - off] : 0;
        __syncthreads();
        sm[t] += x;
        __syncthreads();
    }
    boff[t] = sm[t] - v;
    if (t == 255) dT[0] = sm[t];
}

__global__ __launch_bounds__(256) void place_pts(const float4* __restrict__ pts, int n,
                                                 const int* __restrict__ cellof,
                                                 const int* __restrict__ scnt,
                                                 const int* __restrict__ boff,
                                                 int* __restrict__ cur,
                                                 float* __restrict__ fcomp) {
    int i = blockIdx.x * 256 + threadIdx.x;
    if (i >= n) return;
    int cell = cellof[i];
    if (cell < 0) return;
    int slot = atomicAdd(&cur[cell], 1);
    if (slot >= 32) return;
    int pos = boff[cell >> 8] + scnt[cell] + slot;
    float4 p = pts[i];
    int xi = cell & 255, yi = cell >> 8;
    float cx = (float)xi * 0.4f + -51.0f;
    float cy = (float)yi * 0.4f + -51.0f;
    float4* d = (float4*)(fcomp + (size_t)pos * 8);
    d[0] = make_float4(p.x, p.y, p.z, p.w);
    d[1] = make_float4(p.x - cx, p.y - cy, p.z, 0.f);
}

__global__ __launch_bounds__(256) void mlp_pts(
    const float* __restrict__ fcomp, const int* __restrict__ dT,
    const float* __restrict__ w1, const float* __restrict__ s1, const float* __restrict__ t1,
    const float* __restrict__ w2, const float* __restrict__ s2, const float* __restrict__ t2,
    float* __restrict__ hcomp) {
    int i = blockIdx.x * 256 + threadIdx.x;
    if (i >= dT[0]) return;
    const float4* f = (const float4*)(fcomp + (size_t)i * 8);
    float4 a = f[0], b = f[1];
    float h1[32];
#pragma unroll
    for (int k = 0; k < 32; k++) {
        float v = a.x * w1[0 * 32 + k] + a.y * w1[1 * 32 + k] + a.z * w1[2 * 32 + k]
                + a.w * w1[3 * 32 + k] + b.x * w1[4 * 32 + k] + b.y * w1[5 * 32 + k]
                + b.z * w1[6 * 32 + k];
        h1[k] = fmaxf(v * s1[k] + t1[k], 0.f);
    }
    float acc[64];
#pragma unroll
    for (int c = 0; c < 64; c++) acc[c] = 0.f;
#pragma unroll
    for (int k = 0; k < 32; k++) {
        float hk = h1[k];
#pragma unroll
        for (int c4 = 0; c4 < 16; c4++) {
            float4 wv = *(const float4*)&w2[k * 64 + c4 * 4];
            acc[c4 * 4 + 0] += hk * wv.x;
            acc[c4 * 4 + 1] += hk * wv.y;
            acc[c4 * 4 + 2] += hk * wv.z;
            acc[c4 * 4 + 3] += hk * wv.w;
        }
    }
    float* o = hcomp + (size_t)i * 64;
#pragma unroll
    for (int c4 = 0; c4 < 16; c4++) {
        float4 ov;
        ov.x = fmaxf(acc[c4 * 4 + 0] * s2[c4 * 4 + 0] + t2[c4 * 4 + 0], 0.f);
        ov.y = fmaxf(acc[c4 * 4 + 1] * s2[c4 * 4 + 1] + t2[c4 * 4 + 1], 0.f);
        ov.z = fmaxf(acc[c4 * 4 + 2] * s2[c4 * 4 + 2] + t2[c4 * 4 + 2], 0.f);
        ov.w = fmaxf(acc[c4 * 4 + 3] * s2[c4 * 4 + 3] + t2[c4 * 4 + 3], 0.f);
        *(float4*)&o[c4 * 4] = ov;
    }
}

// Wave per cell; writes desc in conv activation layout:
// [cell][chunk=co>>4][hi u16 x16 | lo u16 x16]
__global__ __launch_bounds__(256) void cell_reduce_v2(
    const int* __restrict__ cnt, const int* __restrict__ scnt,
    const int* __restrict__ boff, const float* __restrict__ hcomp,
    const float* __restrict__ h2z, u16* __restrict__ desc) {
    int cell = blockIdx.x * 4 + (threadIdx.x >> 6);
    int co = threadIdx.x & 63;
    int c = cnt[cell];
    int start = boff[cell >> 8] + scnt[cell];
    int cc = c < 32 ? c : 32;
    float m = (c > 0 && c < 32) ? h2z[co] : 0.f;
    const float* hp = hcomp + (size_t)start * 64 + co;
    for (int s = 0; s < cc; s++) m = fmaxf(m, hp[(size_t)s * 64]);
    u16 h = f2bf(m);
    float hf = __uint_as_float((u32)h << 16);
    u16 l = f2bf(m - hf);
    size_t base = ((size_t)cell * 4 + (co >> 4)) * 32 + (co & 15);
    desc[base] = h;
    desc[base + 16] = l;
}

// ---- MFMA conv v2 ---------------------------------------------------------
// Per 16-ci chunk: one 16x16x32 MFMA computes exact A*W via A_ext=[Ah|Al],
// W_ext=[W|W] (lane k-groups 2,3 read the same W bytes as 0,1).
// Block: 256 thr / 4 waves; pixel tile 16x(TY); co tile 64 (blockIdx.z).
// Wave: MT=TY/4 y-rows x 4 n-tiles. A tile + B panel (all 9 taps) in LDS,
// both XOR-swizzled at 16B granule for conflict-free ds_read_b128.
// Frag maps (verified R7): A row=lane&15, k-grp=(lane>>4); B col=lane&15;
// D col=lane&15, row=(lane>>4)*4+reg.
template <int CIN, int COUT, int TY, bool LAST>
__global__ __launch_bounds__(256) void conv3x3_v2(
    const u16* __restrict__ X, const u16* __restrict__ W,
    const float* __restrict__ bs, const float* __restrict__ bt,
    u16* __restrict__ out, float* __restrict__ outf) {
    constexpr int MT  = TY / 4;
    constexpr int APX = (TY + 2) * 18;
    constexpr int CH  = CIN / 16;
    __shared__ u16 As[APX * 32];     // [pix][hi16|lo16], swizzled 16B slots
    __shared__ u16 Bs[9 * 64 * 16];  // [tap][co][16ci], pair-XOR swizzled

    const int tid = threadIdx.x;
    const int lane = tid & 63, wid = tid >> 6;
    const int r = lane & 15, g = lane >> 4;
    const int bx = blockIdx.x, by = blockIdx.y, cob = blockIdx.z * 64;

    fx4 acc[MT][4];
#pragma unroll
    for (int mt = 0; mt < MT; mt++)
#pragma unroll
        for (int nt = 0; nt < 4; nt++) acc[mt][nt] = (fx4){0.f, 0.f, 0.f, 0.f};

    // per-lane B read base (u16 units), tap-invariant
    int bB[4];
#pragma unroll
    for (int nt = 0; nt < 4; nt++) {
        int col = nt * 16 + r;
        int pr = col >> 1;
        int u = (((col & 1) << 1) | (g & 1)) ^ (pr & 3);
        bB[nt] = pr * 32 + u * 8;
    }

#pragma unroll 1
    for (int c = 0; c < CH; ++c) {
        if (c) __syncthreads();
        // stage A halo tile (zero-pad OOB), swizzled slot = s ^ (p&3)
        for (int i = tid; i < APX * 4; i += 256) {
            int p = i >> 2, s = i & 3;
            int ty = p / 18, tx = p - ty * 18;
            int gy = by * TY + ty - 1, gx = bx * 16 + tx - 1;
            ux4 v = (ux4){0u, 0u, 0u, 0u};
            if (gy >= 0 && gy < NYG && gx >= 0 && gx < NXG)
                v = *(const ux4*)&X[((size_t)(gy * NXG + gx) * CH + c) * 32 + s * 8];
            *(ux4*)&As[p * 32 + ((s ^ (p & 3)) << 3)] = v;
        }
        // stage B panel: 9 taps x 64 co x 32B
        for (int i = tid; i < 9 * 64 * 2; i += 256) {
            int t = i >> 7;
            int rr = i & 127;
            int co = rr >> 1, s = rr & 1;
            ux4 v = *(const ux4*)&W[(((size_t)c * 9 + t) * COUT + cob + co) * 16 + s * 8];
            int pr = co >> 1;
            int u = (((co & 1) << 1) | s) ^ (pr & 3);
            *(ux4*)&Bs[t * 1024 + pr * 32 + u * 8] = v;
        }
        __syncthreads();

#pragma unroll
        for (int t = 0; t < 9; ++t) {
            const int ky = t / 3, kx = t - ky * 3;
            sx8 bf[4], af[MT];
#pragma unroll
            for (int nt = 0; nt < 4; nt++)
                bf[nt] = *(const sx8*)&Bs[t * 1024 + bB[nt]];
#pragma unroll
            for (int mt = 0; mt < MT; mt++) {
                int p = (wid * MT + mt + ky) * 18 + kx + r;
                af[mt] = *(const sx8*)&As[p * 32 + ((g ^ (p & 3)) << 3)];
            }
#pragma unroll
            for (int mt = 0; mt < MT; mt++)
#pragma unroll
                for (int nt = 0; nt < 4; nt++)
                    acc[mt][nt] = __builtin_amdgcn_mfma_f32_16x16x32_bf16(
                        af[mt], bf[nt], acc[mt][nt], 0, 0, 0);
        }
    }

    // epilogue: D col = co-offset (r), row = g*4+ri = x-offset
#pragma unroll
    for (int nt = 0; nt < 4; nt++) {
        int co = cob + nt * 16 + r;
        float sc = bs[co], tb = bt[co];
#pragma unroll
        for (int mt = 0; mt < MT; mt++) {
            int y = by * TY + wid * MT + mt;
            if (LAST) {
                fx4 vv;
#pragma unroll
                for (int ri = 0; ri < 4; ri++)
                    vv[ri] = fmaxf(acc[mt][nt][ri] * sc + tb, 0.f);
                *(fx4*)&outf[((size_t)co << 16) + y * NXG + bx * 16 + g * 4] = vv;
            } else {
#pragma unroll
                for (int ri = 0; ri < 4; ri++) {
                    float v = fmaxf(acc[mt][nt][ri] * sc + tb, 0.f);
                    u16 h = f2bf(v);
                    float hf = __uint_as_float((u32)h << 16);
                    u16 l = f2bf(v - hf);
                    int pix = y * NXG + bx * 16 + g * 4 + ri;
                    size_t base = ((size_t)pix * (COUT / 16) + (co >> 4)) * 32 + (co & 15);
                    out[base] = h;
                    out[base + 16] = l;
                }
            }
        }
    }
}

extern "C" void kernel_launch(void* const* d_in, const int* in_sizes, int n_in,
                              void* d_out, int out_size, void* d_ws, size_t ws_size,
                              hipStream_t stream) {
    const float* points = (const float*)d_in[0];
    const float* w1 = (const float*)d_in[1];
    const float* s1 = (const float*)d_in[2];
    const float* t1 = (const float*)d_in[3];
    const float* w2 = (const float*)d_in[4];
    const float* s2 = (const float*)d_in[5];
    const float* t2 = (const float*)d_in[6];
    const float* cw1a = (const float*)d_in[7];
    const float* cs1a = (const float*)d_in[8];
    const float* ct1a = (const float*)d_in[9];
    const float* cw1b = (const float*)d_in[10];
    const float* cs1b = (const float*)d_in[11];
    const float* ct1b = (const float*)d_in[12];
    const float* cw2a = (const float*)d_in[13];
    const float* cs2a = (const float*)d_in[14];
    const float* ct2a = (const float*)d_in[15];
    const float* cw2b = (const float*)d_in[16];
    const float* cs2b = (const float*)d_in[17];
    const float* ct2b = (const float*)d_in[18];
    int n = in_sizes[0] / 4;

    // Workspace (max 84 MB; 88 proven OK in R8):
    //  <2M  small | 2M..2.8M bf16 weights
    //  4M   fcomp 6.4M [dead after mlp_pts]
    //  4M   desc 16M (4-20M, written by cell_reduce after fcomp dead)
    //  20M  hcomp 51.2M [dead after cell_reduce]
    //  20M  X1 32M (conv1a out, alias hcomp) [dead after conv1b]
    //  52M  X2 32M (conv1b out) [dead after conv2a]
    //  4M   X3 16M (conv2a out, alias desc -- desc dead after conv1a)
    char* ws = (char*)d_ws;
    int*   cnt    = (int*)(ws + 0);
    int*   scnt   = (int*)(ws + 262144);
    int*   cur    = (int*)(ws + 524288);
    int*   boff   = (int*)(ws + 786432);
    int*   dT     = (int*)(ws + 790528);
    float* h2z    = (float*)(ws + 794624);
    int*   cellof = (int*)(ws + (1ull << 20));
    int*   bsum   = (int*)(ws + (1ull << 20) + 819200);
    size_t W0 = 2ull << 20;
    u16* w1a = (u16*)(ws + W0 + 0);       // 4*9*128*16*2  = 147456 B
    u16* w1b = (u16*)(ws + W0 + 196608);  // 8*9*128*16*2  = 294912 B
    u16* w2a = (u16*)(ws + W0 + 524288);  // 8*9*64*16*2   = 147456 B
    u16* w2b = (u16*)(ws + W0 + 688128);  // 4*9*64*16*2   = 73728 B
    float* fcomp = (float*)(ws + (4ull << 20));
    u16*   desc  = (u16*)(ws + (4ull << 20));
    float* hcomp = (float*)(ws + (20ull << 20));
    u16*   X1    = (u16*)(ws + (20ull << 20));
    u16*   X2    = (u16*)(ws + (52ull << 20));
    u16*   X3    = (u16*)(ws + (4ull << 20));

    hipMemsetAsync(cnt, 0, 262144, stream);

    repack_wv2<<<(128 * 64 * 9 + 255) / 256, 256, 0, stream>>>(cw1a, w1a, 64, 128);
    repack_wv2<<<(128 * 128 * 9 + 255) / 256, 256, 0, stream>>>(cw1b, w1b, 128, 128);
    repack_wv2<<<(64 * 128 * 9 + 255) / 256, 256, 0, stream>>>(cw2a, w2a, 128, 64);
    repack_wv2<<<(64 * 64 * 9 + 255) / 256, 256, 0, stream>>>(cw2b, w2b, 64, 64);
    h2zero_k<<<1, 64, 0, stream>>>(t1, w2, s2, t2, h2z);

    count_pts<<<(n + 255) / 256, 256, 0, stream>>>((const float4*)points, n, cnt, cellof);
    scan1<<<256, 256, 0, stream>>>(cnt, scnt, bsum, cur);
    scan2<<<1, 256, 0, stream>>>(bsum, boff, dT);
    place_pts<<<(n + 255) / 256, 256, 0, stream>>>((const float4*)points, n, cellof,
                                                   scnt, boff, cur, fcomp);
    mlp_pts<<<(n + 255) / 256, 256, 0, stream>>>(fcomp, dT, w1, s1, t1, w2, s2, t2, hcomp);
    cell_reduce_v2<<<65536 / 4, 256, 0, stream>>>(cnt, scnt, boff, hcomp, h2z, desc);

    conv3x3_v2<64, 128, 16, false><<<dim3(16, 16, 2), 256, 0, stream>>>(
        desc, w1a, cs1a, ct1a, X1, nullptr);
    conv3x3_v2<128, 128, 16, false><<<dim3(16, 16, 2), 256, 0, stream>>>(
        X1, w1b, cs1b, ct1b, X2, nullptr);
    conv3x3_v2<128, 64, 8, false><<<dim3(16, 32, 1), 256, 0, stream>>>(
        X2, w2a, cs2a, ct2a, X3, nullptr);
    conv3x3_v2<64, 64, 8, true><<<dim3(16, 32, 1), 256, 0, stream>>>(
        X3, w2b, cs2b, ct2b, nullptr, (float*)d_out);
}

// Round 11
// 263.521 us; speedup vs baseline: 2.3154x; 1.1389x over previous
//
#include <hip/hip_runtime.h>
#include <hip/hip_bf16.h>

// ---------------------------------------------------------------------------
// PointPillars encoder.
// R11: single-bf16 activations (drop A-lo plane). R10 was LDS-BW-bound and
//      the A hi/lo split carried 50% redundant payload in every read & MFMA.
//      Now k=32 = 32 real ci per MFMA: MFMA x1/2, LDS reads x1/2, A bytes x1/2.
//      Error ledger: fp32 0.031 -> +W-bf16 0.078 -> +A-bf16 predicted ~0.12
//      (threshold 0.2875; revert to hi/lo A if breached).
// Conv: implicit GEMM, B panel (9 taps) in LDS per 32-ci chunk, XOR-swizzled.
// ---------------------------------------------------------------------------

#define NXG 256
#define NYG 256

typedef unsigned short u16;
typedef unsigned int u32;
typedef __attribute__((ext_vector_type(8))) short sx8;   // 8 bf16 (4 VGPR)
typedef __attribute__((ext_vector_type(4))) float fx4;   // 4 f32
typedef __attribute__((ext_vector_type(4))) u32 ux4;     // 16B

__device__ __forceinline__ u16 f2bf(float x) {           // RNE fp32->bf16
    u32 u = __float_as_uint(x);
    return (u16)((u + 0x7fffu + ((u >> 16) & 1u)) >> 16);
}

// OIHW fp32 -> [ci-chunk32][tap][co][32ci] bf16
__global__ __launch_bounds__(256) void repack_wv3(const float* __restrict__ src,
                                                  u16* __restrict__ dst,
                                                  int Cin, int Cout) {
    int i = blockIdx.x * 256 + threadIdx.x;
    int total = Cout * Cin * 9;
    if (i >= total) return;
    int co = i / (Cin * 9);
    int rr = i - co * (Cin * 9);
    int ci = rr / 9;
    int t  = rr - ci * 9;
    dst[(((size_t)(ci >> 5) * 9 + t) * Cout + co) * 32 + (ci & 31)] = f2bf(src[i]);
}

__global__ void h2zero_k(const float* __restrict__ t1, const float* __restrict__ w2,
                         const float* __restrict__ s2, const float* __restrict__ t2,
                         float* __restrict__ h2z) {
    int co = threadIdx.x;  // 64 threads
    float acc = 0.f;
    for (int j = 0; j < 32; j++) {
        float h1 = fmaxf(t1[j], 0.f);
        acc += h1 * w2[j * 64 + co];
    }
    h2z[co] = fmaxf(acc * s2[co] + t2[co], 0.f);
}

// ---- point stage (unchanged) ----------------------------------------------

__global__ __launch_bounds__(256) void count_pts(const float4* __restrict__ pts, int n,
                                                 int* __restrict__ cnt,
                                                 int* __restrict__ cellof) {
    int i = blockIdx.x * 256 + threadIdx.x;
    if (i >= n) return;
    float4 p = pts[i];
    int cell = -1;
    if (p.x >= -51.2f && p.x < 51.2f && p.y >= -51.2f && p.y < 51.2f) {
        float qx = (p.x + 51.2f) / 0.4f;   // IEEE div matches reference floor
        float qy = (p.y + 51.2f) / 0.4f;
        int xi = (int)floorf(qx); xi = xi < 0 ? 0 : (xi > 255 ? 255 : xi);
        int yi = (int)floorf(qy); yi = yi < 0 ? 0 : (yi > 255 ? 255 : yi);
        cell = yi * NXG + xi;
        atomicAdd(&cnt[cell], 1);
    }
    cellof[i] = cell;
}

__global__ __launch_bounds__(256) void scan1(const int* __restrict__ cnt,
                                             int* __restrict__ scnt,
                                             int* __restrict__ bsum,
                                             int* __restrict__ cur) {
    __shared__ int sm[256];
    int b = blockIdx.x, t = threadIdx.x;
    int v = cnt[b * 256 + t];
    sm[t] = v;
    __syncthreads();
    for (int off = 1; off < 256; off <<= 1) {
        int x = (t >= off) ? sm[t - off] : 0;
        __syncthreads();
        sm[t] += x;
        __syncthreads();
    }
    scnt[b * 256 + t] = sm[t] - v;
    if (t == 255) bsum[b] = sm[t];
    cur[b * 256 + t] = 0;
}

__global__ __launch_bounds__(256) void scan2(const int* __restrict__ bsum,
                                             int* __restrict__ boff,
                                             int* __restrict__ dT) {
    __shared__ int sm[256];
    int t = threadIdx.x;
    int v = bsum[t];
    sm[t] = v;
    __syncthreads();
    for (int off = 1; off < 256; off <<= 1) {
        int x = (t >= off) ? sm[t - off] : 0;
        __syncthreads();
        sm[t] += x;
        __syncthreads();
    }
    boff[t] = sm[t] - v;
    if (t == 255) dT[0] = sm[t];
}

__global__ __launch_bounds__(256) void place_pts(const float4* __restrict__ pts, int n,
                                                 const int* __restrict__ cellof,
                                                 const int* __restrict__ scnt,
                                                 const int* __restrict__ boff,
                                                 int* __restrict__ cur,
                                                 float* __restrict__ fcomp) {
    int i = blockIdx.x * 256 + threadIdx.x;
    if (i >= n) return;
    int cell = cellof[i];
    if (cell < 0) return;
    int slot = atomicAdd(&cur[cell], 1);
    if (slot >= 32) return;
    int pos = boff[cell >> 8] + scnt[cell] + slot;
    float4 p = pts[i];
    int xi = cell & 255, yi = cell >> 8;
    float cx = (float)xi * 0.4f + -51.0f;
    float cy = (float)yi * 0.4f + -51.0f;
    float4* d = (float4*)(fcomp + (size_t)pos * 8);
    d[0] = make_float4(p.x, p.y, p.z, p.w);
    d[1] = make_float4(p.x - cx, p.y - cy, p.z, 0.f);
}

__global__ __launch_bounds__(256) void mlp_pts(
    const float* __restrict__ fcomp, const int* __restrict__ dT,
    const float* __restrict__ w1, const float* __restrict__ s1, const float* __restrict__ t1,
    const float* __restrict__ w2, const float* __restrict__ s2, const float* __restrict__ t2,
    float* __restrict__ hcomp) {
    int i = blockIdx.x * 256 + threadIdx.x;
    if (i >= dT[0]) return;
    const float4* f = (const float4*)(fcomp + (size_t)i * 8);
    float4 a = f[0], b = f[1];
    float h1[32];
#pragma unroll
    for (int k = 0; k < 32; k++) {
        float v = a.x * w1[0 * 32 + k] + a.y * w1[1 * 32 + k] + a.z * w1[2 * 32 + k]
                + a.w * w1[3 * 32 + k] + b.x * w1[4 * 32 + k] + b.y * w1[5 * 32 + k]
                + b.z * w1[6 * 32 + k];
        h1[k] = fmaxf(v * s1[k] + t1[k], 0.f);
    }
    float acc[64];
#pragma unroll
    for (int c = 0; c < 64; c++) acc[c] = 0.f;
#pragma unroll
    for (int k = 0; k < 32; k++) {
        float hk = h1[k];
#pragma unroll
        for (int c4 = 0; c4 < 16; c4++) {
            float4 wv = *(const float4*)&w2[k * 64 + c4 * 4];
            acc[c4 * 4 + 0] += hk * wv.x;
            acc[c4 * 4 + 1] += hk * wv.y;
            acc[c4 * 4 + 2] += hk * wv.z;
            acc[c4 * 4 + 3] += hk * wv.w;
        }
    }
    float* o = hcomp + (size_t)i * 64;
#pragma unroll
    for (int c4 = 0; c4 < 16; c4++) {
        float4 ov;
        ov.x = fmaxf(acc[c4 * 4 + 0] * s2[c4 * 4 + 0] + t2[c4 * 4 + 0], 0.f);
        ov.y = fmaxf(acc[c4 * 4 + 1] * s2[c4 * 4 + 1] + t2[c4 * 4 + 1], 0.f);
        ov.z = fmaxf(acc[c4 * 4 + 2] * s2[c4 * 4 + 2] + t2[c4 * 4 + 2], 0.f);
        ov.w = fmaxf(acc[c4 * 4 + 3] * s2[c4 * 4 + 3] + t2[c4 * 4 + 3], 0.f);
        *(float4*)&o[c4 * 4] = ov;
    }
}

// Wave per cell; writes desc as plain bf16 NHWC [cell][64].
__global__ __launch_bounds__(256) void cell_reduce_v3(
    const int* __restrict__ cnt, const int* __restrict__ scnt,
    const int* __restrict__ boff, const float* __restrict__ hcomp,
    const float* __restrict__ h2z, u16* __restrict__ desc) {
    int cell = blockIdx.x * 4 + (threadIdx.x >> 6);
    int co = threadIdx.x & 63;
    int c = cnt[cell];
    int start = boff[cell >> 8] + scnt[cell];
    int cc = c < 32 ? c : 32;
    float m = (c > 0 && c < 32) ? h2z[co] : 0.f;
    const float* hp = hcomp + (size_t)start * 64 + co;
    for (int s = 0; s < cc; s++) m = fmaxf(m, hp[(size_t)s * 64]);
    desc[(size_t)cell * 64 + co] = f2bf(m);
}

// ---- MFMA conv v3 ---------------------------------------------------------
// bf16 x bf16 -> fp32, k=32 real ci per MFMA. Block: 4 waves, 16xTY pixels,
// 64 co. Wave: MT=TY/4 m-tiles x 4 n-tiles. Per 32-ci chunk: A halo tile
// (APX x 64B) + B panel (9 taps x 64co x 64B) staged in LDS, XOR-swizzled
// at 16B granule (A: slot^(p&3); B: slot^((co>>1)&3)) -> bank-uniform b128.
// Frag maps (verified R7/R10): A row=lane&15, k=(lane>>4)*8+j;
// B col=lane&15, k=(lane>>4)*8+j; D col=lane&15, row=(lane>>4)*4+reg.
template <int CIN, int COUT, int TY, bool LAST>
__global__ __launch_bounds__(256) void conv3x3_v3(
    const u16* __restrict__ X, const u16* __restrict__ W,
    const float* __restrict__ bs, const float* __restrict__ bt,
    u16* __restrict__ out, float* __restrict__ outf) {
    constexpr int MT  = TY / 4;
    constexpr int APX = (TY + 2) * 18;
    constexpr int CH  = CIN / 32;
    __shared__ u16 As[APX * 32];      // [pix][32ci], 4 swizzled 16B slots/pix
    __shared__ u16 Bs[9 * 64 * 32];   // [tap][co][32ci], swizzled

    const int tid = threadIdx.x;
    const int lane = tid & 63, wid = tid >> 6;
    const int r = lane & 15, g = lane >> 4;
    const int bx = blockIdx.x, by = blockIdx.y, cob = blockIdx.z * 64;

    fx4 acc[MT][4];
#pragma unroll
    for (int mt = 0; mt < MT; mt++)
#pragma unroll
        for (int nt = 0; nt < 4; nt++) acc[mt][nt] = (fx4){0.f, 0.f, 0.f, 0.f};

    // per-lane B read base (u16 units), tap-invariant:
    // co = nt*16+r; data slot g lives at u = g ^ ((co>>1)&3) = g ^ ((r>>1)&3)
    int bB[4];
    {
        int u = (g ^ ((r >> 1) & 3)) << 3;
#pragma unroll
        for (int nt = 0; nt < 4; nt++) bB[nt] = (nt * 16 + r) * 32 + u;
    }

#pragma unroll 1
    for (int c = 0; c < CH; ++c) {
        if (c) __syncthreads();
        // stage A halo tile (zero-pad OOB); pixel p slot s -> s^(p&3)
        for (int i = tid; i < APX * 4; i += 256) {
            int p = i >> 2, s = i & 3;
            int ty = p / 18, tx = p - ty * 18;
            int gy = by * TY + ty - 1, gx = bx * 16 + tx - 1;
            ux4 v = (ux4){0u, 0u, 0u, 0u};
            if (gy >= 0 && gy < NYG && gx >= 0 && gx < NXG)
                v = *(const ux4*)&X[((size_t)(gy * NXG + gx) * CH + c) * 32 + s * 8];
            *(ux4*)&As[p * 32 + ((s ^ (p & 3)) << 3)] = v;
        }
        // stage B panel: 9 taps x 64 co x 64B; co slot s -> s^((co>>1)&3)
        for (int i = tid; i < 9 * 64 * 4; i += 256) {
            int t = i >> 8;
            int rr = i & 255;
            int co = rr >> 2, s = rr & 3;
            ux4 v = *(const ux4*)&W[(((size_t)c * 9 + t) * COUT + cob + co) * 32 + s * 8];
            *(ux4*)&Bs[t * 2048 + co * 32 + ((s ^ ((co >> 1) & 3)) << 3)] = v;
        }
        __syncthreads();

#pragma unroll
        for (int t = 0; t < 9; ++t) {
            const int ky = t / 3, kx = t - ky * 3;
            sx8 bf[4], af[MT];
#pragma unroll
            for (int nt = 0; nt < 4; nt++)
                bf[nt] = *(const sx8*)&Bs[t * 2048 + bB[nt]];
#pragma unroll
            for (int mt = 0; mt < MT; mt++) {
                int p = (wid * MT + mt + ky) * 18 + kx + r;
                af[mt] = *(const sx8*)&As[p * 32 + ((g ^ (p & 3)) << 3)];
            }
#pragma unroll
            for (int mt = 0; mt < MT; mt++)
#pragma unroll
                for (int nt = 0; nt < 4; nt++)
                    acc[mt][nt] = __builtin_amdgcn_mfma_f32_16x16x32_bf16(
                        af[mt], bf[nt], acc[mt][nt], 0, 0, 0);
        }
    }

    // epilogue: D col = co-offset (r), row = g*4+ri = x-offset
#pragma unroll
    for (int nt = 0; nt < 4; nt++) {
        int co = cob + nt * 16 + r;
        float sc = bs[co], tb = bt[co];
#pragma unroll
        for (int mt = 0; mt < MT; mt++) {
            int y = by * TY + wid * MT + mt;
            if (LAST) {
                fx4 vv;
#pragma unroll
                for (int ri = 0; ri < 4; ri++)
                    vv[ri] = fmaxf(acc[mt][nt][ri] * sc + tb, 0.f);
                *(fx4*)&outf[((size_t)co << 16) + y * NXG + bx * 16 + g * 4] = vv;
            } else {
#pragma unroll
                for (int ri = 0; ri < 4; ri++) {
                    float v = fmaxf(acc[mt][nt][ri] * sc + tb, 0.f);
                    int pix = y * NXG + bx * 16 + g * 4 + ri;
                    out[(size_t)pix * COUT + co] = f2bf(v);
                }
            }
        }
    }
}

extern "C" void kernel_launch(void* const* d_in, const int* in_sizes, int n_in,
                              void* d_out, int out_size, void* d_ws, size_t ws_size,
                              hipStream_t stream) {
    const float* points = (const float*)d_in[0];
    const float* w1 = (const float*)d_in[1];
    const float* s1 = (const float*)d_in[2];
    const float* t1 = (const float*)d_in[3];
    const float* w2 = (const float*)d_in[4];
    const float* s2 = (const float*)d_in[5];
    const float* t2 = (const float*)d_in[6];
    const float* cw1a = (const float*)d_in[7];
    const float* cs1a = (const float*)d_in[8];
    const float* ct1a = (const float*)d_in[9];
    const float* cw1b = (const float*)d_in[10];
    const float* cs1b = (const float*)d_in[11];
    const float* ct1b = (const float*)d_in[12];
    const float* cw2a = (const float*)d_in[13];
    const float* cs2a = (const float*)d_in[14];
    const float* ct2a = (const float*)d_in[15];
    const float* cw2b = (const float*)d_in[16];
    const float* cs2b = (const float*)d_in[17];
    const float* ct2b = (const float*)d_in[18];
    int n = in_sizes[0] / 4;

    // Workspace (peak 71.2 MB; 88 proven OK):
    //  <2M  small | 2M..2.7M bf16 weights
    //  4M   fcomp 6.4M [dead after mlp_pts]
    //  4M   X3 8M (conv2a out; fcomp+desc dead by then)
    //  12M  desc 8M bf16 [dead after conv1a]
    //  20M  hcomp 51.2M [dead after cell_reduce]
    //  20M  X1 16M bf16 (conv1a out, alias hcomp) [dead after conv1b]
    //  36M  X2 16M bf16 (conv1b out, alias hcomp) [dead after conv2a]
    char* ws = (char*)d_ws;
    int*   cnt    = (int*)(ws + 0);
    int*   scnt   = (int*)(ws + 262144);
    int*   cur    = (int*)(ws + 524288);
    int*   boff   = (int*)(ws + 786432);
    int*   dT     = (int*)(ws + 790528);
    float* h2z    = (float*)(ws + 794624);
    int*   cellof = (int*)(ws + (1ull << 20));
    int*   bsum   = (int*)(ws + (1ull << 20) + 819200);
    size_t W0 = 2ull << 20;
    u16* w1a = (u16*)(ws + W0 + 0);       // 2*9*128*32*2 = 147456 B
    u16* w1b = (u16*)(ws + W0 + 147456);  // 4*9*128*32*2 = 294912 B
    u16* w2a = (u16*)(ws + W0 + 442368);  // 4*9*64*32*2  = 147456 B
    u16* w2b = (u16*)(ws + W0 + 589824);  // 2*9*64*32*2  = 73728 B
    float* fcomp = (float*)(ws + (4ull << 20));
    u16*   X3    = (u16*)(ws + (4ull << 20));
    u16*   desc  = (u16*)(ws + (12ull << 20));
    float* hcomp = (float*)(ws + (20ull << 20));
    u16*   X1    = (u16*)(ws + (20ull << 20));
    u16*   X2    = (u16*)(ws + (36ull << 20));

    hipMemsetAsync(cnt, 0, 262144, stream);

    repack_wv3<<<(128 * 64 * 9 + 255) / 256, 256, 0, stream>>>(cw1a, w1a, 64, 128);
    repack_wv3<<<(128 * 128 * 9 + 255) / 256, 256, 0, stream>>>(cw1b, w1b, 128, 128);
    repack_wv3<<<(64 * 128 * 9 + 255) / 256, 256, 0, stream>>>(cw2a, w2a, 128, 64);
    repack_wv3<<<(64 * 64 * 9 + 255) / 256, 256, 0, stream>>>(cw2b, w2b, 64, 64);
    h2zero_k<<<1, 64, 0, stream>>>(t1, w2, s2, t2, h2z);

    count_pts<<<(n + 255) / 256, 256, 0, stream>>>((const float4*)points, n, cnt, cellof);
    scan1<<<256, 256, 0, stream>>>(cnt, scnt, bsum, cur);
    scan2<<<1, 256, 0, stream>>>(bsum, boff, dT);
    place_pts<<<(n + 255) / 256, 256, 0, stream>>>((const float4*)points, n, cellof,
                                                   scnt, boff, cur, fcomp);
    mlp_pts<<<(n + 255) / 256, 256, 0, stream>>>(fcomp, dT, w1, s1, t1, w2, s2, t2, hcomp);
    cell_reduce_v3<<<65536 / 4, 256, 0, stream>>>(cnt, scnt, boff, hcomp, h2z, desc);

    conv3x3_v3<64, 128, 16, false><<<dim3(16, 16, 2), 256, 0, stream>>>(
        desc, w1a, cs1a, ct1a, X1, nullptr);
    conv3x3_v3<128, 128, 16, false><<<dim3(16, 16, 2), 256, 0, stream>>>(
        X1, w1b, cs1b, ct1b, X2, nullptr);
    conv3x3_v3<128, 64, 8, false><<<dim3(16, 32, 1), 256, 0, stream>>>(
        X2, w2a, cs2a, ct2a, X3, nullptr);
    conv3x3_v3<64, 64, 8, true><<<dim3(16, 32, 1), 256, 0, stream>>>(
        X3, w2b, cs2b, ct2b, nullptr, (float*)d_out);
}